// Round 5
// baseline (3794.052 us; speedup 1.0000x reference)
//
#include <hip/hip_runtime.h>
#include <math.h>

namespace {
constexpr int NB  = 512;   // batch
constexpr int NT  = 128;   // timesteps
constexpr int NY  = 16;    // obs dim
constexpr int NZ  = 32;    // latent dim
constexpr int NK  = 8;     // mixture
constexpr int NH  = 64;    // hidden
constexpr int NSUB = 2;    // euler substeps (structural constant in reference)
constexpr float FJIT = 1e-5f;
constexpr float CLOG2PI = 1.8378770664093453f;
}

// Factor the 8x8 lower block at (c0,c0) of src (row stride lds) entirely in
// one thread's registers; write L to dst (row stride ldd) and 1/diag to sinvp.
__device__ __forceinline__ void chol8_1t(const float* src, int lds,
                                         float* dst, int ldd,
                                         int c0, float* sinvp) {
  float a[8][8];
  #pragma unroll
  for (int r = 0; r < 8; ++r)
    #pragma unroll
    for (int c = 0; c <= r; ++c) a[r][c] = src[(c0 + r) * lds + (c0 + c)];
  float iv[8];
  #pragma unroll
  for (int j = 0; j < 8; ++j) {
    const float d  = sqrtf(a[j][j]);
    const float id = 1.0f / d;
    iv[j] = id; a[j][j] = d;
    #pragma unroll
    for (int r = j + 1; r < 8; ++r) a[r][j] *= id;
    #pragma unroll
    for (int k = j + 1; k < 8; ++k)
      #pragma unroll
      for (int r = k; r < 8; ++r) a[r][k] -= a[r][j] * a[k][j];
  }
  #pragma unroll
  for (int r = 0; r < 8; ++r) {
    #pragma unroll
    for (int c = 0; c <= r; ++c) dst[(c0 + r) * ldd + (c0 + c)] = a[r][c];
    sinvp[c0 + r] = iv[r];
  }
}

// Like chol8_1t, but first subtracts the immediately-preceding panel product:
// a[r][c] = mat[c0+r][c0+c] - sum_q dst[c0+r][c0-8+q]*dst[c0+c][c0-8+q].
// (All OTHER panels' contributions must already be applied to mat.)
__device__ __forceinline__ void chol8_trail_1t(const float* mat, int ld,
                                               float* dst, int ldd,
                                               int c0, float* sinvp) {
  float a[8][8];
  #pragma unroll
  for (int r = 0; r < 8; ++r)
    #pragma unroll
    for (int c = 0; c <= r; ++c) {
      float s = mat[(c0 + r) * ld + (c0 + c)];
      #pragma unroll
      for (int q = 0; q < 8; ++q)
        s -= dst[(c0 + r) * ldd + (c0 - 8 + q)] * dst[(c0 + c) * ldd + (c0 - 8 + q)];
      a[r][c] = s;
    }
  float iv[8];
  #pragma unroll
  for (int j = 0; j < 8; ++j) {
    const float d  = sqrtf(a[j][j]);
    const float id = 1.0f / d;
    iv[j] = id; a[j][j] = d;
    #pragma unroll
    for (int r = j + 1; r < 8; ++r) a[r][j] *= id;
    #pragma unroll
    for (int k = j + 1; k < 8; ++k)
      #pragma unroll
      for (int r = k; r < 8; ++r) a[r][k] -= a[r][j] * a[k][j];
  }
  #pragma unroll
  for (int r = 0; r < 8; ++r) {
    #pragma unroll
    for (int c = 0; c <= r; ++c) dst[(c0 + r) * ldd + (c0 + c)] = a[r][c];
    sinvp[c0 + r] = iv[r];
  }
}

// Panel row solve: w = L_diag^{-1} * src[i][c0..c0+7], write to dst[i][c0..c0+7].
__device__ __forceinline__ void panel_row(const float* src, int lds,
                                          float* dst, int ldd,
                                          int c0, int i, const float* sinvp) {
  float w[8];
  #pragma unroll
  for (int q = 0; q < 8; ++q) w[q] = src[i * lds + c0 + q];
  #pragma unroll
  for (int q = 0; q < 8; ++q) {
    float s = w[q];
    #pragma unroll
    for (int p = 0; p < q; ++p) s -= dst[(c0 + q) * ldd + (c0 + p)] * w[p];
    w[q] = s * sinvp[c0 + q];
  }
  #pragma unroll
  for (int q = 0; q < 8; ++q) dst[i * ldd + c0 + q] = w[q];
}

// One block (256 threads) per batch element; all state in LDS (~69 KB -> 2 blocks/CU).
// Barriers/timestep: ph1(1) ph2+chol8(1) chol16 panel/trail(2) ph4(1) ph5'(1)
// ph7+chol8(1) chol32(6) ph9(1) euler(2x3) = 20.
// In-phase chol8 fusions rely on per-wave in-order DS execution: the 8x8 block
// tid0 factors is produced exclusively by wave-0 lanes earlier in program order.
__global__ __launch_bounds__(256, 2)
void kf_scan_kernel(const float* __restrict__ gy,
                    const float* __restrict__ gmask,
                    const float* __restrict__ gtimes,
                    const float* __restrict__ gmu0,
                    const float* __restrict__ gSig0d,
                    const float* __restrict__ gH,
                    const float* __restrict__ gRd,
                    const float* __restrict__ gAb,
                    const float* __restrict__ gW1,
                    const float* __restrict__ gb1,
                    const float* __restrict__ gW2,
                    const float* __restrict__ gb2,
                    const float* __restrict__ gQd,
                    float* __restrict__ out_mus,
                    float* __restrict__ out_Ls,
                    float* __restrict__ out_lp)
{
  const int b   = blockIdx.x;
  const int tid = threadIdx.x;
  const int i8  = tid >> 3;         // 0..31  (row for 32x32 work)
  const int j8  = (tid & 7) << 2;   // 0,4,..,28 (4-col group)

  __shared__ float sAb[NK][NZ][NZ+1];   // padded: conflict-free A-mix reads
  __shared__ float sW1[NZ][NH];
  __shared__ float sH [NY][NZ+1];       // padded: conflict-free row-dot reads
  __shared__ float sW2[NH][NK];
  __shared__ float sb1v[NH];
  __shared__ float sb2v[NK];
  __shared__ float sRd[NY];
  __shared__ float sQd[NZ];
  __shared__ float Sig[NZ][NZ+1];       // carried covariance
  __shared__ float Wk [NZ][NZ+1];       // Sigma_u (lower) / chol32 workspace
  __shared__ float T1 [NZ][NZ+1];       // ImKH / A
  __shared__ float T2 [NZ][NZ+1];       // chol32 L output / A@Sig temp
  __shared__ float HP [NY][NZ+1];
  __shared__ float Sm [NY][NY+1];       // S / chol16 workspace
  __shared__ float SL [NY][NY+1];       // chol(S) (lower + diag valid)
  __shared__ float Kg [NZ][NY+1];       // Kalman gain (z,y)
  __shared__ float muv[NZ], muu[NZ], innov[NY], hidv[NH], alphav[NK];
  __shared__ float siv[NZ];             // 1/diag for chol + solves
  __shared__ float lpt;

  double lpacc = 0.0;                   // tid0-only log-prob accumulator

  // ---- stage constants into LDS ----
  for (int idx = tid; idx < NK*NZ*NZ; idx += 256) {
    const int k = idx >> 10, r = (idx >> 5) & 31, c = idx & 31;
    sAb[k][r][c] = gAb[idx];
  }
  for (int idx = tid; idx < NZ*NH; idx += 256) ((float*)sW1)[idx] = gW1[idx];
  for (int idx = tid; idx < NY*NZ; idx += 256) {
    const int r = idx >> 5, c = idx & 31;
    sH[r][c] = gH[idx];
  }
  for (int idx = tid; idx < NH*NK; idx += 256) ((float*)sW2)[idx] = gW2[idx];
  if (tid < NH) sb1v[tid] = gb1[tid];
  if (tid < NK) sb2v[tid] = gb2[tid];
  if (tid < NY) sRd[tid]  = gRd[tid];
  if (tid < NZ) sQd[tid]  = gQd[tid];
  if (tid < NZ) {
    muv[tid] = gmu0[tid];
    for (int j = 0; j < NZ; ++j) Sig[tid][j] = 0.0f;
    const float r = sqrtf(gSig0d[tid]);   // Sigma = L0 @ L0^T, L0 = diag(sqrt(s0))
    Sig[tid][tid] = r * r;
  }
  const float dtv = gtimes[1] - gtimes[0];
  const float h   = dtv / (float)NSUB;

  float yreg = (tid < NY) ? gy[(size_t)b*NT*NY + tid] : 0.0f;  // y[t=0]
  __syncthreads();

  #pragma unroll 1
  for (int t = 0; t < NT; ++t) {
    const float m = gmask[(size_t)b*NT + t];

    // ---- ph1: innovation + HP = H @ Sig ----
    if (tid < NY) {
      float s = 0.f;
      #pragma unroll
      for (int k = 0; k < NZ; ++k) s += sH[tid][k] * muv[k];
      innov[tid] = yreg - s;
    }
    {
      const int i16 = tid >> 4, c0 = (tid & 15) << 1;
      float s0 = 0.f, s1 = 0.f;
      #pragma unroll
      for (int k = 0; k < NZ; ++k) {
        const float hv = sH[i16][k];
        s0 += hv * Sig[k][c0];
        s1 += hv * Sig[k][c0+1];
      }
      HP[i16][c0] = s0; HP[i16][c0+1] = s1;
    }
    __syncthreads();

    // ---- ph2: S = HP@H^T + R + JIT, wave0 owns top-left 8x8; fold chol8(0).
    //      Also prefetch y[t+1]. ----
    if (tid < NY && t + 1 < NT) yreg = gy[((size_t)b*NT + t + 1)*NY + tid];
    {
      int r, c;
      if (tid < 64)       { r = tid >> 3;              c = tid & 7; }
      else if (tid < 128) { r = (tid - 64) >> 3;       c = 8 + ((tid - 64) & 7); }
      else                { r = 8 + ((tid - 128) >> 4); c = (tid - 128) & 15; }
      float s = 0.f;
      #pragma unroll
      for (int k = 0; k < NZ; ++k) s += HP[r][k] * sH[c][k];
      if (r == c) s += sRd[r] + FJIT;
      Sm[r][c] = s;
    }
    if (tid == 0) chol8_1t(&Sm[0][0], NY+1, &SL[0][0], NY+1, 0, siv);  // wave0 data
    __syncthreads();

    // ---- chol16 rest: panel, then trailing+factor (tid0) ----
    if (tid < 8) panel_row(&Sm[0][0], NY+1, &SL[0][0], NY+1, 0, 8 + tid, siv);
    __syncthreads();
    if (tid == 0) chol8_trail_1t(&Sm[0][0], NY+1, &SL[0][0], NY+1, 8, siv);
    __syncthreads();

    // ---- ph4: solve S X = HP -> Kg = X^T ; mu_u ; logprob (wave 1) ----
    if (tid < NZ) {
      const int c = tid;
      float s[NY], v[NY];
      #pragma unroll
      for (int i = 0; i < NY; ++i) s[i] = HP[i][c];
      #pragma unroll
      for (int i = 0; i < NY; ++i) {          // forward: L v = rhs
        const float vi = s[i] * siv[i];
        v[i] = vi;
        #pragma unroll
        for (int jj = i+1; jj < NY; ++jj) s[jj] -= SL[jj][i] * vi;
      }
      float x[NY];
      #pragma unroll
      for (int i = NY-1; i >= 0; --i) {       // backward: L^T x = v
        const float xi = v[i] * siv[i];
        x[i] = xi;
        #pragma unroll
        for (int jj = 0; jj < i; ++jj) v[jj] -= SL[i][jj] * xi;
      }
      float acc = 0.f;
      #pragma unroll
      for (int i = 0; i < NY; ++i) { Kg[c][i] = x[i]; acc += x[i] * innov[i]; }
      muu[c] = muv[c] + acc;                  // mu_u folded into solve phase
    } else if (tid == 64) {  // wave 1: w = LS^{-1} innov, logprob
      float s[NY];
      #pragma unroll
      for (int i = 0; i < NY; ++i) s[i] = innov[i];
      float sw = 0.f, prod = 1.f;
      #pragma unroll
      for (int i = 0; i < NY; ++i) {
        const float wi = s[i] * siv[i];
        sw += wi * wi;
        prod *= SL[i][i];
        #pragma unroll
        for (int jj = i+1; jj < NY; ++jj) s[jj] -= SL[jj][i] * wi;
      }
      lpt = -0.5f * (sw + NY * CLOG2PI) - logf(prod);
    }
    __syncthreads();

    // ---- ph5': T1 = I - Kg@H ; T2 = ImKH@Sig == Sig - Kg@HP (fused) ----
    {
      #pragma unroll
      for (int q = 0; q < 4; ++q) {
        const int j = j8 + q;
        float s1 = (i8 == j) ? 1.0f : 0.0f;
        float s2 = Sig[i8][j];
        #pragma unroll
        for (int yy = 0; yy < NY; ++yy) {
          const float kv = Kg[i8][yy];
          s1 -= kv * sH[yy][j];
          s2 -= kv * HP[yy][j];
        }
        T1[i8][j] = s1;
        T2[i8][j] = s2;
      }
    }
    __syncthreads();

    // ---- ph7: Wk(lower) = T2@ImKH^T + Kg R Kg^T + JIT ; fold chol8(blk0)
    //      (Wk rows 0..7 are produced by wave 0 => tid0 may factor in-phase) ----
    {
      #pragma unroll
      for (int q = 0; q < 4; ++q) {
        const int j = j8 + q;
        if (j <= i8) {
          float s = 0.f;
          #pragma unroll
          for (int k = 0; k < NZ; ++k) s += T2[i8][k] * T1[j][k];
          float s2 = 0.f;
          #pragma unroll
          for (int yy = 0; yy < NY; ++yy) s2 += Kg[i8][yy] * sRd[yy] * Kg[j][yy];
          s += s2;
          if (i8 == j) s += FJIT;
          Wk[i8][j] = s;
        }
      }
    }
    if (tid == 0) chol8_1t(&Wk[0][0], NZ+1, &T2[0][0], NZ+1, 0, siv);
    __syncthreads();

    // ---- chol32 rest: 3 x {panel | parallel-trailing + tid0 next diag} ----
    // Coverage: panel-b's contribution to entry (i,k>=c0+8,k<=i) is applied by
    // the parallel region when i>=c0+16, by chol8_trail (next diag) otherwise.
    #pragma unroll 1
    for (int blkb = 0; blkb < 3; ++blkb) {
      const int c0 = blkb << 3;
      if (tid < 24 - c0) panel_row(&Wk[0][0], NZ+1, &T2[0][0], NZ+1, c0, c0 + 8 + tid, siv);
      __syncthreads();
      if (i8 >= c0 + 16) {
        #pragma unroll
        for (int q4 = 0; q4 < 4; ++q4) {
          const int k = j8 + q4;
          if (k >= c0 + 8 && k <= i8) {
            float s = Wk[i8][k];
            #pragma unroll
            for (int q = 0; q < 8; ++q) s -= T2[i8][c0+q] * T2[k][c0+q];
            Wk[i8][k] = s;
          }
        }
      }
      if (tid == 0) chol8_trail_1t(&Wk[0][0], NZ+1, &T2[0][0], NZ+1, c0 + 8, siv);
      __syncthreads();
    }

    // ---- ph9: outputs, Sig = L@L^T, mu blend ; wave0: MLP for substep 0 ----
    if (tid < NZ) {
      const float nm = m * muu[tid] + (1.0f - m) * muv[tid];
      out_mus[((size_t)t*NB + b)*NZ + tid] = nm;
      muv[tid] = nm;
    }
    if (tid == 0) lpacc += (double)(m * lpt);
    {
      float4 lv;
      lv.x = (j8+0 <= i8) ? T2[i8][j8+0] : 0.0f;
      lv.y = (j8+1 <= i8) ? T2[i8][j8+1] : 0.0f;
      lv.z = (j8+2 <= i8) ? T2[i8][j8+2] : 0.0f;
      lv.w = (j8+3 <= i8) ? T2[i8][j8+3] : 0.0f;
      *(float4*)&out_Ls[(((size_t)t*NB + b)*NZ + i8)*NZ + j8] = lv;
      #pragma unroll
      for (int q = 0; q < 4; ++q) {
        const int j = j8 + q;
        const int km = (i8 < j) ? i8 : j;
        float s = 0.f;
        for (int k = 0; k <= km; ++k) s += T2[i8][k] * T2[j][k];
        Sig[i8][j] = s;
      }
    }
    // wave 0: MLP -> alphav (muv is wave0-written; per-wave in-order LDS)
    if (tid < NH) {
      __builtin_amdgcn_sched_barrier(0);
      float sacc = sb1v[tid];
      #pragma unroll
      for (int k = 0; k < NZ; ++k) sacc += muv[k] * sW1[k][tid];
      hidv[tid] = tanhf(sacc);
      __builtin_amdgcn_sched_barrier(0);
      const int kk = tid & 7, r0 = (tid >> 3) << 3;
      float part = 0.f;
      #pragma unroll
      for (int j = 0; j < 8; ++j) part += hidv[r0 + j] * sW2[r0 + j][kk];
      part += __shfl_xor(part, 8);
      part += __shfl_xor(part, 16);
      part += __shfl_xor(part, 32);
      float lg[NK];
      #pragma unroll
      for (int q = 0; q < NK; ++q) lg[q] = __shfl(part, (tid & 56) | q) + sb2v[q];
      float mx = lg[0];
      #pragma unroll
      for (int q = 1; q < NK; ++q) mx = fmaxf(mx, lg[q]);
      float se = 0.f;
      #pragma unroll
      for (int q = 0; q < NK; ++q) { lg[q] = expf(lg[q] - mx); se += lg[q]; }
      const float inv = 1.0f / se;
      if (tid == 0) {
        #pragma unroll
        for (int q = 0; q < NK; ++q) alphav[q] = lg[q] * inv;
      }
    }
    __syncthreads();

    // ---- Euler substeps (pred chol skipped: chol(X)@chol(X)^T == X) ----
    #pragma unroll 1
    for (int ss = 0; ss < NSUB; ++ss) {
      // A = sum_k alpha_k A_base[k] -> T1
      {
        #pragma unroll
        for (int q = 0; q < 4; ++q) {
          const int j = j8 + q;
          float s = 0.f;
          #pragma unroll
          for (int k = 0; k < NK; ++k) s += alphav[k] * sAb[k][i8][j];
          T1[i8][j] = s;
        }
      }
      __syncthreads();
      // mu2 = mu + h*A@mu ; T2 = A @ Sig
      if (tid < NZ) {
        float s = 0.f;
        #pragma unroll
        for (int k = 0; k < NZ; ++k) s += T1[tid][k] * muv[k];
        muu[tid] = muv[tid] + h * s;
      }
      {
        float a0=0.f, a1=0.f, a2=0.f, a3=0.f;
        #pragma unroll
        for (int k = 0; k < NZ; ++k) {
          const float a = T1[i8][k];
          a0 += a * Sig[k][j8];
          a1 += a * Sig[k][j8+1];
          a2 += a * Sig[k][j8+2];
          a3 += a * Sig[k][j8+3];
        }
        T2[i8][j8] = a0; T2[i8][j8+1] = a1; T2[i8][j8+2] = a2; T2[i8][j8+3] = a3;
      }
      __syncthreads();
      // Sig += h*(T2 + T2^T) + diag(h*Q + JIT) ; mu = mu2 ; wave0: next MLP
      {
        #pragma unroll
        for (int q = 0; q < 4; ++q) {
          const int j = j8 + q;
          float s = Sig[i8][j] + h * (T2[i8][j] + T2[j][i8]);
          if (i8 == j) s += h * sQd[i8] + FJIT;
          Sig[i8][j] = s;
        }
      }
      if (tid < NZ) muv[tid] = muu[tid];
      if (ss == 0 && tid < NH) {
        __builtin_amdgcn_sched_barrier(0);
        float sacc = sb1v[tid];
        #pragma unroll
        for (int k = 0; k < NZ; ++k) sacc += muv[k] * sW1[k][tid];  // wave0-local
        hidv[tid] = tanhf(sacc);
        __builtin_amdgcn_sched_barrier(0);
        const int kk = tid & 7, r0 = (tid >> 3) << 3;
        float part = 0.f;
        #pragma unroll
        for (int j = 0; j < 8; ++j) part += hidv[r0 + j] * sW2[r0 + j][kk];
        part += __shfl_xor(part, 8);
        part += __shfl_xor(part, 16);
        part += __shfl_xor(part, 32);
        float lg[NK];
        #pragma unroll
        for (int q = 0; q < NK; ++q) lg[q] = __shfl(part, (tid & 56) | q) + sb2v[q];
        float mx = lg[0];
        #pragma unroll
        for (int q = 1; q < NK; ++q) mx = fmaxf(mx, lg[q]);
        float se = 0.f;
        #pragma unroll
        for (int q = 0; q < NK; ++q) { lg[q] = expf(lg[q] - mx); se += lg[q]; }
        const float inv = 1.0f / se;
        if (tid == 0) {
          #pragma unroll
          for (int q = 0; q < NK; ++q) alphav[q] = lg[q] * inv;
        }
      }
      __syncthreads();
    }
  }

  if (tid == 0) out_lp[b] = (float)lpacc;
}

extern "C" void kernel_launch(void* const* d_in, const int* in_sizes, int n_in,
                              void* d_out, int out_size, void* d_ws, size_t ws_size,
                              hipStream_t stream) {
  (void)in_sizes; (void)n_in; (void)d_ws; (void)ws_size; (void)out_size;
  const float* gy     = (const float*)d_in[0];
  const float* gmask  = (const float*)d_in[1];
  const float* gtimes = (const float*)d_in[2];
  const float* gmu0   = (const float*)d_in[3];
  const float* gS0d   = (const float*)d_in[4];
  const float* gH     = (const float*)d_in[5];
  const float* gRd    = (const float*)d_in[6];
  const float* gAb    = (const float*)d_in[7];
  const float* gW1    = (const float*)d_in[8];
  const float* gb1    = (const float*)d_in[9];
  const float* gW2    = (const float*)d_in[10];
  const float* gb2    = (const float*)d_in[11];
  const float* gQd    = (const float*)d_in[12];
  // d_in[13] = n_sub (==2, structural constant)

  float* out = (float*)d_out;
  float* out_mus = out;                                          // (T,B,32)
  float* out_Ls  = out + (size_t)NT*NB*NZ;                       // (T,B,32,32)
  float* out_lp  = out + (size_t)NT*NB*NZ + (size_t)NT*NB*NZ*NZ; // (B,)

  kf_scan_kernel<<<NB, 256, 0, stream>>>(gy, gmask, gtimes, gmu0, gS0d, gH, gRd,
                                         gAb, gW1, gb1, gW2, gb2, gQd,
                                         out_mus, out_Ls, out_lp);
}